// Round 6
// baseline (66.550 us; speedup 1.0000x reference)
//
#include <hip/hip_runtime.h>

// KNNInteractionGraph — single fused kernel, row-per-wave, spill-free hot path.
// N=8192, K=32, CUTOFF=10, batch sorted (molecules contiguous, n ~ 64+-8).
//
// One wave per row r:
//   - molecule range [start,end) via ballot window-scan over batch (2 coalesced
//     loads); deep binary search only in a noinline cold helper
//   - lane owns column c = 64j+lane (j<NCH), distance in registers
//   - stable rank (value asc, index asc) via v_readlane broadcast sweep
//   - hot path: NCH=1/2 inline (n<=128). n>128: noinline cold fallback so its
//     register pressure cannot force spills into the hot path under the
//     64-VGPR cap from __launch_bounds__(256, 8).
//
// Output (float32, 3*N*K): [indices | centers | weights].

#define CUTOFF_F 10.0f
#define ROWS_PER_BLOCK 4

__device__ __forceinline__ float readlane_f(float v, int lane) {
    return __int_as_float(__builtin_amdgcn_readlane(__float_as_int(v), lane));
}
__device__ __forceinline__ int readlane_i(int v, int lane) {
    return __builtin_amdgcn_readlane(v, lane);
}

// Reference-exact masked distance (gram expansion, f32, no FMA contraction):
__device__ __forceinline__ float dist_v(float4 pr, float4 pc, bool diag) {
    if (diag) return CUTOFF_F;
    float dot = __fadd_rn(__fadd_rn(__fmul_rn(pr.x, pc.x), __fmul_rn(pr.y, pc.y)),
                          __fmul_rn(pr.z, pc.z));
    float sq = __fsub_rn(__fadd_rn(pr.w, pc.w), __fadd_rn(dot, dot));
    sq = fmaxf(sq, 0.0f);
    float d = (sq > 0.0f) ? __fsqrt_rn(sq) : 0.0f;
    return (d > CUTOFF_F) ? CUTOFF_F : d;
}

__device__ __forceinline__ float4 load_pos4(const float* __restrict__ pos, int g) {
    float x = pos[g * 3 + 0];
    float y = pos[g * 3 + 1];
    float z = pos[g * 3 + 2];
    float sq = __fadd_rn(__fadd_rn(__fmul_rn(x, x), __fmul_rn(y, y)), __fmul_rn(z, z));
    return make_float4(x, y, z, sq);
}

// ---------------- hot row core: columns in registers, n <= 64*NCH -------------
template <int NCH>
__device__ __forceinline__ void row_core_reg(const float* __restrict__ pos,
                                             float4 pr, int n, int lane,
                                             int start, int end, int r,
                                             float* __restrict__ out,
                                             int NK, int K) {
    float v[NCH];
    int   rk[NCH];
#pragma unroll
    for (int j = 0; j < NCH; ++j) {
        const int c = 64 * j + lane;
        v[j]  = (c < n) ? dist_v(pr, load_pos4(pos, start + c), (start + c) == r)
                        : CUTOFF_F;
        rk[j] = 0;
    }
    // stable rank sweep: broadcast column g's value (uniform lane index)
#pragma unroll
    for (int jj = 0; jj < NCH; ++jj) {
        const int base = 64 * jj;
        const int lim  = (NCH == 1) ? n : min(n - base, 64);
#pragma unroll 4
        for (int cc = 0; cc < lim; ++cc) {
            const float vv = readlane_f(v[jj], cc);
            const int   g  = base + cc;
#pragma unroll
            for (int j = 0; j < NCH; ++j) {
                const int c = 64 * j + lane;
                rk[j] += (vv < v[j]) || (vv == v[j] && g < c);  // (value asc, idx asc)
            }
        }
    }
    int m = 0;
#pragma unroll
    for (int j = 0; j < NCH; ++j) {
        const int c = 64 * j + lane;
        m += __popcll(__ballot(c < n && v[j] < CUTOFF_F));
    }
#pragma unroll
    for (int j = 0; j < NCH; ++j) {
        const int c = 64 * j + lane;
        if (c < n && v[j] < CUTOFF_F && rk[j] < K) {
            const int o = r * K + rk[j];
            out[o]          = (float)(start + c);
            out[2 * NK + o] = v[j];
        }
    }
    for (int k2 = lane; k2 < K; k2 += 64)     // centers chunk
        out[NK + r * K + k2] = (float)r;
    // fill slots [m,K): CUTOFF at globally-smallest masked indices
    // {0..start-1} U {in-mol masked} U {end..N-1}  (lax.top_k tie order).
    // Cold with these inputs (all in-mol distances < 10 -> m = n-1 >= K).
    if (m < K) {
        const int mm = n - m;                 // in-mol masked count (incl diag)
        for (int fb = 0; fb < K - m; fb += 64) {
            const int t = fb + lane;
            const bool active = t < (K - m);
            int idx = 0;
            bool found = false;
            if (active) {
                if (t < start)            { idx = t;                      found = true; }
                else if (t - start >= mm) { idx = end + (t - start - mm); found = true; }
            }
            if (__any(active && !found)) {
                int cnt = 0;
#pragma unroll
                for (int jj = 0; jj < NCH; ++jj) {
                    const int base = 64 * jj;
                    const int lim  = min(n - base, 64);
                    for (int cc = 0; cc < lim; ++cc) {
                        if (readlane_f(v[jj], cc) == CUTOFF_F) {
                            if (active && !found && cnt == t - start) {
                                idx = start + base + cc; found = true;
                            }
                            ++cnt;
                        }
                    }
                }
            }
            if (active) {
                const int o = r * K + m + t;
                out[o]          = (float)idx;
                out[2 * NK + o] = CUTOFF_F;
            }
        }
    }
}

// ------------- cold paths: own register allocation (noinline) -----------------
__device__ __attribute__((noinline))
int lower_bound_cold(const int* __restrict__ batch, int lo, int hi, int key) {
    while (lo < hi) {
        int mid = (lo + hi) >> 1;
        if (batch[mid] < key) lo = mid + 1; else hi = mid;
    }
    return lo;
}

__device__ __attribute__((noinline))
void row_core_fallback(const float* __restrict__ pos, float4 pr, int n, int lane,
                       int start, int end, int r, float* __restrict__ out,
                       int NK, int K) {
    // generic global-recompute path, correct for any n (never taken here)
    int m = 0;
    for (int cb = 0; cb < n; cb += 64) {
        const int c = cb + lane;
        const float v = (c < n)
            ? dist_v(pr, load_pos4(pos, start + c), (start + c) == r) : CUTOFF_F;
        int rk = 0;
        for (int cc = 0; cc < n; ++cc) {
            const float vv = dist_v(pr, load_pos4(pos, start + cc), (start + cc) == r);
            rk += (vv < v) || (vv == v && cc < c);
        }
        if (c < n && v < CUTOFF_F && rk < K) {
            const int o = r * K + rk;
            out[o]          = (float)(start + c);
            out[2 * NK + o] = v;
        }
        m += __popcll(__ballot(c < n && v < CUTOFF_F));
    }
    for (int k2 = lane; k2 < K; k2 += 64)
        out[NK + r * K + k2] = (float)r;
    if (m < K) {
        const int mm = n - m;
        for (int fb = 0; fb < K - m; fb += 64) {
            const int t = fb + lane;
            const bool active = t < (K - m);
            int idx = 0; bool found = false;
            if (active) {
                if (t < start)            { idx = t;                      found = true; }
                else if (t - start >= mm) { idx = end + (t - start - mm); found = true; }
            }
            if (__any(active && !found)) {
                int cnt = 0;
                for (int cc = 0; cc < n; ++cc) {
                    if (dist_v(pr, load_pos4(pos, start + cc), (start + cc) == r)
                        == CUTOFF_F) {
                        if (active && !found && cnt == t - start) {
                            idx = start + cc; found = true;
                        }
                        ++cnt;
                    }
                }
            }
            if (active) {
                const int o = r * K + m + t;
                out[o]          = (float)idx;
                out[2 * NK + o] = CUTOFF_F;
            }
        }
    }
}

// ---------------- kernel ------------------------------------------------------
__global__ __launch_bounds__(256, 8)
void knn_fused_kernel(const float* __restrict__ pos,
                      const int* __restrict__ batch,
                      float* __restrict__ out,
                      int N, int K) {
    const int w    = threadIdx.x >> 6;
    const int lane = threadIdx.x & 63;
    const int r    = blockIdx.x * ROWS_PER_BLOCK + w;
    if (r >= N) return;                       // no LDS, no barriers
    const int NK = N * K;

    // issue all independent loads up front (chain depth 1)
    const int iu = r - 63 + lane;             // upward window: idx r-63 .. r
    const int id = r + 1 + lane;              // downward window: idx r+1 .. r+64
    const int au = batch[max(iu, 0)];
    const int ad = batch[min(id, N - 1)];
    const float4 pr = load_pos4(pos, r);

    const int b = readlane_i(au, 63);         // batch[r]

    // start: leading-ones run of the upward match mask
    const unsigned long long mu = __ballot(iu >= 0 && au == b);   // bit63 always set
    int start;
    if (mu != ~0ull) {
        start = r - __builtin_clzll(~mu) + 1;
    } else {
        const int iu2 = r - 127 + lane;
        const unsigned long long mu2 =
            __ballot(iu2 >= 0 && batch[max(iu2, 0)] == b);
        if (mu2 != ~0ull)           start = r - 63 - __builtin_clzll(~mu2);
        else if (r - 127 <= 0)      start = 0;
        else                        start = lower_bound_cold(batch, 0, r, b);
    }

    // end: trailing-ones run of the downward match mask
    const unsigned long long md = __ballot(id < N && ad == b);
    int end;
    if (md != ~0ull) {
        end = r + 1 + __builtin_ctzll(~md);
    } else {
        const int id2 = r + 65 + lane;
        const unsigned long long md2 =
            __ballot(id2 < N && batch[min(id2, N - 1)] == b);
        if (md2 != ~0ull)           end = r + 65 + __builtin_ctzll(~md2);
        else if (r + 129 >= N)      end = N;
        else                        end = lower_bound_cold(batch, r + 1, N, b + 1);
    }

    const int n = end - start;

    if      (n <= 64)  row_core_reg<1>(pos, pr, n, lane, start, end, r, out, NK, K);
    else if (n <= 128) row_core_reg<2>(pos, pr, n, lane, start, end, r, out, NK, K);
    else               row_core_fallback(pos, pr, n, lane, start, end, r, out, NK, K);
}

extern "C" void kernel_launch(void* const* d_in, const int* in_sizes, int n_in,
                              void* d_out, int out_size, void* d_ws, size_t ws_size,
                              hipStream_t stream) {
    const float* pos   = (const float*)d_in[0];   // [N,3] float32
    const int*   batch = (const int*)d_in[1];     // [N]   int32, sorted
    float*       out   = (float*)d_out;           // float32, 3*N*K

    const int N = in_sizes[1];            // 8192
    const int K = out_size / (3 * N);     // 32

    const int grid = (N + ROWS_PER_BLOCK - 1) / ROWS_PER_BLOCK;  // 2048
    knn_fused_kernel<<<grid, 256, 0, stream>>>(pos, batch, out, N, K);
}